// Round 4
// baseline (730.800 us; speedup 1.0000x reference)
//
#include <hip/hip_runtime.h>

#define C_CH 4096
#define CPB 8                 // channels per block
#define NBLK (C_CH / CPB)     // 512 blocks
#define THREADS 1024
#define CHUNK_IDS 32768       // ids scanned per chunk
#define QCAP 768              // LDS queue capacity (mean fill 64, >50 sigma headroom)

typedef float f32x2 __attribute__((ext_vector_type(2)));

__global__ __launch_bounds__(THREADS) void fused_channel_agg(
        const float* __restrict__ z, const int* __restrict__ y,
        const int* __restrict__ ids, float* __restrict__ out, int B) {
    __shared__ float acc[CPB * 128];
    __shared__ int cnt[CPB];
    __shared__ int first[CPB];
    __shared__ int queue[QCAP];
    __shared__ int qn;

    const int tid  = threadIdx.x;
    const int b    = blockIdx.x;
    const int wave = tid >> 6;
    const int lane = tid & 63;

    for (int i = tid; i < CPB * 128; i += THREADS) acc[i] = 0.f;
    if (tid < CPB) { cnt[tid] = 0; first[tid] = B - 1; }
    if (tid == 0) qn = 0;
    __syncthreads();

    const f32x2* z2 = (const f32x2*)z;
    const int nchunks = (B + CHUNK_IDS - 1) / CHUNK_IDS;

    for (int ch = 0; ch < nchunks; ++ch) {
        const int base = ch * CHUNK_IDS;
        // ---- scan phase: 8 int4 loads per thread, coalesced ----
        #pragma unroll
        for (int k = 0; k < 8; ++k) {
            int i4 = (base >> 2) + k * THREADS + tid;
            int rowbase = i4 * 4;
            if (rowbase + 3 < B) {
                int4 v = ((const int4*)ids)[i4];
                int cc0 = v.x, cc1 = v.y, cc2 = v.z, cc3 = v.w;
                if ((cc0 >> 3) == b) {
                    int s = cc0 & 7; int row = rowbase;
                    atomicMin(&first[s], row); atomicAdd(&cnt[s], 1);
                    int pos = atomicAdd(&qn, 1);
                    if (pos < QCAP) queue[pos] = (row << 3) | s;
                    else for (int t = 0; t < 64; ++t) {
                        f32x2 vv = z2[(size_t)row * 64 + t];
                        atomicAdd(&acc[s * 128 + 2 * t], vv.x);
                        atomicAdd(&acc[s * 128 + 2 * t + 1], vv.y);
                    }
                }
                if ((cc1 >> 3) == b) {
                    int s = cc1 & 7; int row = rowbase + 1;
                    atomicMin(&first[s], row); atomicAdd(&cnt[s], 1);
                    int pos = atomicAdd(&qn, 1);
                    if (pos < QCAP) queue[pos] = (row << 3) | s;
                    else for (int t = 0; t < 64; ++t) {
                        f32x2 vv = z2[(size_t)row * 64 + t];
                        atomicAdd(&acc[s * 128 + 2 * t], vv.x);
                        atomicAdd(&acc[s * 128 + 2 * t + 1], vv.y);
                    }
                }
                if ((cc2 >> 3) == b) {
                    int s = cc2 & 7; int row = rowbase + 2;
                    atomicMin(&first[s], row); atomicAdd(&cnt[s], 1);
                    int pos = atomicAdd(&qn, 1);
                    if (pos < QCAP) queue[pos] = (row << 3) | s;
                    else for (int t = 0; t < 64; ++t) {
                        f32x2 vv = z2[(size_t)row * 64 + t];
                        atomicAdd(&acc[s * 128 + 2 * t], vv.x);
                        atomicAdd(&acc[s * 128 + 2 * t + 1], vv.y);
                    }
                }
                if ((cc3 >> 3) == b) {
                    int s = cc3 & 7; int row = rowbase + 3;
                    atomicMin(&first[s], row); atomicAdd(&cnt[s], 1);
                    int pos = atomicAdd(&qn, 1);
                    if (pos < QCAP) queue[pos] = (row << 3) | s;
                    else for (int t = 0; t < 64; ++t) {
                        f32x2 vv = z2[(size_t)row * 64 + t];
                        atomicAdd(&acc[s * 128 + 2 * t], vv.x);
                        atomicAdd(&acc[s * 128 + 2 * t + 1], vv.y);
                    }
                }
            } else {
                for (int j = 0; j < 4; ++j) {
                    int row = rowbase + j;
                    if (row < B) {
                        int c = ids[row];
                        if ((c >> 3) == b) {
                            int s = c & 7;
                            atomicMin(&first[s], row); atomicAdd(&cnt[s], 1);
                            int pos = atomicAdd(&qn, 1);
                            if (pos < QCAP) queue[pos] = (row << 3) | s;
                            else for (int t = 0; t < 64; ++t) {
                                f32x2 vv = z2[(size_t)row * 64 + t];
                                atomicAdd(&acc[s * 128 + 2 * t], vv.x);
                                atomicAdd(&acc[s * 128 + 2 * t + 1], vv.y);
                            }
                        }
                    }
                }
            }
        }
        __syncthreads();
        // ---- gather phase: waves process queue, 4 rows in flight each ----
        const int n = min(qn, QCAP);
        for (int qb = wave * 4; qb < n; qb += 64) {
            int m = min(4, n - qb);
            f32x2 vv[4]; int sl[4];
            #pragma unroll
            for (int k = 0; k < 4; ++k) {
                if (k < m) {
                    int e = queue[qb + k];
                    int row = e >> 3; sl[k] = e & 7;
                    vv[k] = __builtin_nontemporal_load(&z2[(size_t)row * 64 + lane]);
                }
            }
            #pragma unroll
            for (int k = 0; k < 4; ++k) {
                if (k < m) {
                    atomicAdd(&acc[sl[k] * 128 + 2 * lane], vv[k].x);
                    atomicAdd(&acc[sl[k] * 128 + 2 * lane + 1], vv[k].y);
                }
            }
        }
        __syncthreads();
        if (tid == 0) qn = 0;
        __syncthreads();
    }

    // ---- epilogue ----
    if (tid < CPB * 128) {
        int slot = tid >> 7, col = tid & 127;
        int c = b * CPB + slot;
        out[(size_t)c * 128 + col] = acc[tid] / (float)max(cnt[slot], 1);
    }
    if (tid < CPB) {
        int c = b * CPB + tid;
        out[(size_t)C_CH * 128 + c] = (float)y[min(first[tid], B - 1)];
    }
}

extern "C" void kernel_launch(void* const* d_in, const int* in_sizes, int n_in,
                              void* d_out, int out_size, void* d_ws, size_t ws_size,
                              hipStream_t stream) {
    const float* z   = (const float*)d_in[0];
    const int*   y   = (const int*)d_in[1];
    const int*   ids = (const int*)d_in[2];
    float* out = (float*)d_out;
    const int B = in_sizes[2];

    fused_channel_agg<<<NBLK, THREADS, 0, stream>>>(z, y, ids, out, B);
}

// Round 5
// 692.353 us; speedup vs baseline: 1.0555x; 1.0555x over previous
//
#include <hip/hip_runtime.h>

#define C_CH 4096
#define CPB 8                 // channels per block
#define NBLK (C_CH / CPB)     // 512 blocks
#define THREADS 1024
#define QCAP 1536             // matches/block: mean 1024, sigma 32 -> +16 sigma

typedef float f32x2 __attribute__((ext_vector_type(2)));

__global__ __launch_bounds__(THREADS, 8) void fused_channel_agg(
        const float* __restrict__ z, const int* __restrict__ y,
        const int* __restrict__ ids, float* __restrict__ out, int B) {
    __shared__ float acc[CPB * 128];
    __shared__ int cnt[CPB];
    __shared__ int first[CPB];
    __shared__ int queue[QCAP];
    __shared__ int qn;

    const int tid  = threadIdx.x;
    const int b    = blockIdx.x;
    const int wave = tid >> 6;
    const int lane = tid & 63;
    const f32x2* z2 = (const f32x2*)z;

    for (int i = tid; i < CPB * 128; i += THREADS) acc[i] = 0.f;
    if (tid < CPB) { cnt[tid] = 0; first[tid] = B - 1; }
    if (tid == 0) qn = 0;
    __syncthreads();

    // slow-path accumulate (statistically never hit; correctness only)
    auto spill_row = [&](int s, int row) {
        for (int t = 0; t < 64; ++t) {
            f32x2 vv = z2[(size_t)row * 64 + t];
            atomicAdd(&acc[s * 128 + 2 * t],     vv.x);
            atomicAdd(&acc[s * 128 + 2 * t + 1], vv.y);
        }
    };
    auto push = [&](int c, int row) {
        if ((c >> 3) != b) return;
        int s = c & 7;
        atomicMin(&first[s], row);
        atomicAdd(&cnt[s], 1);
        int pos = atomicAdd(&qn, 1);
        if (pos < QCAP) queue[pos] = (row << 3) | s;
        else spill_row(s, row);
    };

    // ---- scan phase: ONE pass over all ids, 4-deep register pipeline ----
    const int4* ids4 = (const int4*)ids;
    const int nI4 = B >> 2;
    for (int i = tid; i < nI4; i += THREADS * 4) {
        int4 v[4]; int have[4];
        #pragma unroll
        for (int k = 0; k < 4; ++k) {
            int idx = i + k * THREADS;
            have[k] = (idx < nI4);
            if (have[k]) v[k] = ids4[idx];
        }
        #pragma unroll
        for (int k = 0; k < 4; ++k) {
            if (!have[k]) continue;
            int rowbase = (i + k * THREADS) * 4;
            push(v[k].x, rowbase + 0);
            push(v[k].y, rowbase + 1);
            push(v[k].z, rowbase + 2);
            push(v[k].w, rowbase + 3);
        }
    }
    // tail rows (B not multiple of 4)
    for (int row = (nI4 << 2) + tid; row < B; row += THREADS) push(ids[row], row);

    __syncthreads();

    // ---- gather phase: each wave keeps 8 x 512B nontemporal loads in flight ----
    const int n = min(qn, QCAP);
    for (int qb = wave * 8; qb < n; qb += 16 * 8) {
        int m = min(8, n - qb);
        f32x2 vv[8]; int sl[8];
        #pragma unroll
        for (int k = 0; k < 8; ++k) {
            if (k < m) {
                int e = queue[qb + k];
                sl[k] = e & 7;
                vv[k] = __builtin_nontemporal_load(&z2[(size_t)(e >> 3) * 64 + lane]);
            }
        }
        #pragma unroll
        for (int k = 0; k < 8; ++k) {
            if (k < m) {
                atomicAdd(&acc[sl[k] * 128 + 2 * lane],     vv[k].x);
                atomicAdd(&acc[sl[k] * 128 + 2 * lane + 1], vv[k].y);
            }
        }
    }
    __syncthreads();

    // ---- epilogue ----
    if (tid < CPB * 128) {
        int slot = tid >> 7, col = tid & 127;
        out[(size_t)(b * CPB + slot) * 128 + col] = acc[tid] / (float)max(cnt[slot], 1);
    }
    if (tid < CPB) {
        out[(size_t)C_CH * 128 + b * CPB + tid] = (float)y[min(first[tid], B - 1)];
    }
}

extern "C" void kernel_launch(void* const* d_in, const int* in_sizes, int n_in,
                              void* d_out, int out_size, void* d_ws, size_t ws_size,
                              hipStream_t stream) {
    const float* z   = (const float*)d_in[0];
    const int*   y   = (const int*)d_in[1];
    const int*   ids = (const int*)d_in[2];
    float* out = (float*)d_out;
    const int B = in_sizes[2];

    fused_channel_agg<<<NBLK, THREADS, 0, stream>>>(z, y, ids, out, B);
}

// Round 6
// 427.906 us; speedup vs baseline: 1.7079x; 1.6180x over previous
//
#include <hip/hip_runtime.h>

#define C_CH 4096
#define D_DIM 128

typedef float f32x2 __attribute__((ext_vector_type(2)));

// ---------------- K0: init first[] ----------------
__global__ __launch_bounds__(256) void init_kernel(int* first, int B) {
    int i = blockIdx.x * blockDim.x + threadIdx.x;
    if (i < C_CH) first[i] = B - 1;
}

// ---------------- K1: count + first via global atomics (int4, 4 ids/thread) ----
__global__ __launch_bounds__(256) void count_kernel(const int* __restrict__ ids,
                                                    int* cnt, int* first, int B) {
    int t = blockIdx.x * blockDim.x + threadIdx.x;
    int row = t * 4;
    if (row + 3 < B) {
        int4 v = ((const int4*)ids)[t];
        atomicAdd(&cnt[v.x], 1); atomicMin(&first[v.x], row + 0);
        atomicAdd(&cnt[v.y], 1); atomicMin(&first[v.y], row + 1);
        atomicAdd(&cnt[v.z], 1); atomicMin(&first[v.z], row + 2);
        atomicAdd(&cnt[v.w], 1); atomicMin(&first[v.w], row + 3);
    } else {
        for (int k = 0; k < 4; ++k)
            if (row + k < B) { int c = ids[row + k]; atomicAdd(&cnt[c], 1); atomicMin(&first[c], row + k); }
    }
}

// ---------------- K2: exclusive scan of 4096 counts -> offs, cursor ----------
__global__ void scan_kernel(const int* __restrict__ cnt, int* offs, int* cursor) {
    __shared__ int wtot[16];
    int tid  = threadIdx.x;
    int lane = tid & 63;
    int wave = tid >> 6;
    int base = tid * 4;
    int v0 = cnt[base + 0], v1 = cnt[base + 1], v2 = cnt[base + 2], v3 = cnt[base + 3];
    int s = v0 + v1 + v2 + v3;
    int inc = s;
    for (int off = 1; off < 64; off <<= 1) {
        int n = __shfl_up(inc, off, 64);
        if (lane >= off) inc += n;
    }
    if (lane == 63) wtot[wave] = inc;
    __syncthreads();
    if (wave == 0) {
        int t = (lane < 16) ? wtot[lane] : 0;
        int ts = t;
        for (int off = 1; off < 16; off <<= 1) {
            int n = __shfl_up(ts, off, 64);
            if (lane >= off) ts += n;
        }
        if (lane < 16) wtot[lane] = ts - t;
    }
    __syncthreads();
    int run = wtot[wave] + (inc - s);
    offs[base + 0] = run; cursor[base + 0] = run; run += v0;
    offs[base + 1] = run; cursor[base + 1] = run; run += v1;
    offs[base + 2] = run; cursor[base + 2] = run; run += v2;
    offs[base + 3] = run; cursor[base + 3] = run; run += v3;
    if (tid == 1023) offs[C_CH] = run;   // == B
}

// ---------------- K3: scatter row indices into channel-sorted order ----------
__global__ __launch_bounds__(256) void scatter_kernel(const int* __restrict__ ids,
                                                      int* cursor, int* order, int B) {
    int t = blockIdx.x * blockDim.x + threadIdx.x;
    int row = t * 4;
    if (row + 3 < B) {
        int4 v = ((const int4*)ids)[t];
        int p0 = atomicAdd(&cursor[v.x], 1);
        int p1 = atomicAdd(&cursor[v.y], 1);
        int p2 = atomicAdd(&cursor[v.z], 1);
        int p3 = atomicAdd(&cursor[v.w], 1);
        order[p0] = row + 0;
        order[p1] = row + 1;
        order[p2] = row + 2;
        order[p3] = row + 3;
    } else {
        for (int k = 0; k < 4; ++k)
            if (row + k < B) { int pos = atomicAdd(&cursor[ids[row + k]], 1); order[pos] = row + k; }
    }
}

// ---------------- K4: reduce — one WAVE per channel, 16 rows in flight --------
// lane owns columns (2*lane, 2*lane+1): each row = one 512B wave-load.
// Tail uses clamped indices + masked accumulate so loads stay batched (no serial tail).
__global__ __launch_bounds__(256) void reduce_kernel(
        const float* __restrict__ z, const int* __restrict__ order,
        const int* __restrict__ offs, const int* __restrict__ first,
        const int* __restrict__ y, float* __restrict__ out, int B) {
    int w = blockIdx.x * 4 + (threadIdx.x >> 6);   // channel
    int lane = threadIdx.x & 63;
    if (w >= C_CH) return;
    int beg = offs[w], end = offs[w + 1];
    const f32x2* z2 = (const f32x2*)z;

    f32x2 a0 = {0.f, 0.f}, a1 = {0.f, 0.f}, a2 = {0.f, 0.f}, a3 = {0.f, 0.f};
    f32x2 a4 = {0.f, 0.f}, a5 = {0.f, 0.f}, a6 = {0.f, 0.f}, a7 = {0.f, 0.f};

    if (end > beg) {
        for (int r = beg; r < end; r += 16) {
            int idx[16];
            #pragma unroll
            for (int k = 0; k < 16; ++k)
                idx[k] = order[min(r + k, end - 1)];      // clamped: always valid
            f32x2 v[16];
            #pragma unroll
            for (int k = 0; k < 16; ++k)
                v[k] = __builtin_nontemporal_load(&z2[(size_t)idx[k] * 64 + lane]);
            #pragma unroll
            for (int k = 0; k < 16; ++k) {
                if (r + k < end) {
                    switch (k & 7) {
                        case 0: a0 += v[k]; break;
                        case 1: a1 += v[k]; break;
                        case 2: a2 += v[k]; break;
                        case 3: a3 += v[k]; break;
                        case 4: a4 += v[k]; break;
                        case 5: a5 += v[k]; break;
                        case 6: a6 += v[k]; break;
                        case 7: a7 += v[k]; break;
                    }
                }
            }
        }
    }
    f32x2 sum = ((a0 + a1) + (a2 + a3)) + ((a4 + a5) + (a6 + a7));
    int cnt_c = end - beg;
    float inv = 1.f / (float)max(cnt_c, 1);
    f32x2 res; res.x = sum.x * inv; res.y = sum.y * inv;
    ((f32x2*)out)[(size_t)w * 64 + lane] = res;
    if (lane == 0) {
        out[(size_t)C_CH * D_DIM + w] = (float)y[min(first[w], B - 1)];
    }
}

// ---------------- launch ----------------
extern "C" void kernel_launch(void* const* d_in, const int* in_sizes, int n_in,
                              void* d_out, int out_size, void* d_ws, size_t ws_size,
                              hipStream_t stream) {
    const float* z   = (const float*)d_in[0];
    const int*   y   = (const int*)d_in[1];
    const int*   ids = (const int*)d_in[2];
    float* out = (float*)d_out;
    const int B = in_sizes[2];

    // workspace layout (ints): cnt | offs(+pad) | cursor | first | order
    int* cnt    = (int*)d_ws;           // 4096  (must be zeroed: harness poisons ws)
    int* offs   = cnt + C_CH;           // 4097 (+3 pad)
    int* cursor = offs + C_CH + 4;      // 4096
    int* first  = cursor + C_CH;        // 4096
    int* order  = first + C_CH;         // B

    hipMemsetAsync(cnt, 0, C_CH * sizeof(int), stream);
    init_kernel<<<(C_CH + 255) / 256, 256, 0, stream>>>(first, B);
    int tquads = (B + 3) / 4;
    count_kernel<<<(tquads + 255) / 256, 256, 0, stream>>>(ids, cnt, first, B);
    scan_kernel<<<1, 1024, 0, stream>>>(cnt, offs, cursor);
    scatter_kernel<<<(tquads + 255) / 256, 256, 0, stream>>>(ids, cursor, order, B);
    reduce_kernel<<<C_CH / 4, 256, 0, stream>>>(z, order, offs, first, y, out, B);
}